// Round 1
// baseline (3155.232 us; speedup 1.0000x reference)
//
#include <hip/hip_runtime.h>

// ---------------------------------------------------------------------------
// StructuralCoherenceLoss on MI355X
// Inputs:  d_in[0] structure        int32  [64,32,32,32]
//          d_in[1] block_embeddings f32    [64,32,32,32,32]  (B,C,X,Y,Z)
// Output:  d_out   f32 [5] = (total, l_conn, l_patch, l_smooth, l_support)
// Workspace accumulators (double): 0 isolated, 1 na, 2 unsupported,
//                                  3 entropy, 4 dx, 5 dy, 6 dz
// ---------------------------------------------------------------------------

__device__ __forceinline__ bool non_air(int t) {
    return !(t == 102 || t == 576 || t == 3352);
}

__device__ __forceinline__ float wave_reduce_f(float v) {
    #pragma unroll
    for (int off = 32; off > 0; off >>= 1) v += __shfl_down(v, off, 64);
    return v;
}

__device__ __forceinline__ int wave_reduce_i(int v) {
    #pragma unroll
    for (int off = 32; off > 0; off >>= 1) v += __shfl_down(v, off, 64);
    return v;
}

// --- connectivity + support (structure is 8 MB; neighbor loads hit L1/L2) ---
__global__ void struct_kernel(const int* __restrict__ s, double* __restrict__ acc) {
    const int idx = blockIdx.x * blockDim.x + threadIdx.x;   // 2,097,152 voxels
    const int z = idx & 31;
    const int y = (idx >> 5) & 31;
    const int x = (idx >> 10) & 31;

    int iso = 0, unsup = 0, nai = 0;
    const int t = s[idx];
    const bool na = non_air(t);
    if (na) {
        nai = 1;
        int ncnt = 0;
        bool below_na = false;
        if (x > 0)  ncnt += non_air(s[idx - 1024]);
        if (x < 31) ncnt += non_air(s[idx + 1024]);
        if (y > 0)  { below_na = non_air(s[idx - 32]); ncnt += below_na; }
        if (y < 31) ncnt += non_air(s[idx + 32]);
        if (z > 0)  ncnt += non_air(s[idx - 1]);
        if (z < 31) ncnt += non_air(s[idx + 1]);
        iso   = (ncnt == 0) ? 1 : 0;
        unsup = (y > 0 && !below_na) ? 1 : 0;   // bottom layer excluded
    }

    iso   = wave_reduce_i(iso);
    nai   = wave_reduce_i(nai);
    unsup = wave_reduce_i(unsup);

    __shared__ int smem[3][4];
    const int lane = threadIdx.x & 63, wid = threadIdx.x >> 6;
    if (lane == 0) { smem[0][wid] = iso; smem[1][wid] = nai; smem[2][wid] = unsup; }
    __syncthreads();
    if (threadIdx.x == 0) {
        int a = smem[0][0] + smem[0][1] + smem[0][2] + smem[0][3];
        int b = smem[1][0] + smem[1][1] + smem[1][2] + smem[1][3];
        int c = smem[2][0] + smem[2][1] + smem[2][2] + smem[2][3];
        if (a) atomicAdd(&acc[0], (double)a);
        atomicAdd(&acc[1], (double)b);
        if (c) atomicAdd(&acc[2], (double)c);
    }
}

// --- per-patch entropy: one wave per 4x4x4 patch, lane = one token ----------
__global__ void patch_kernel(const int* __restrict__ s, double* __restrict__ acc) {
    const int gtid = blockIdx.x * blockDim.x + threadIdx.x;
    const int pid  = gtid >> 6;            // 32768 patches
    const int lane = threadIdx.x & 63;

    // patch id -> (b, ix, iy, iz); lane -> (px, py, pz), flat = px*16+py*4+pz
    const int b   = pid >> 9;
    const int rem = pid & 511;
    const int ix = rem >> 6, iy = (rem >> 3) & 7, iz = rem & 7;
    const int px = lane >> 4, py = (lane >> 2) & 3, pz = lane & 3;
    const int x = ix * 4 + px, y = iy * 4 + py, z = iz * 4 + pz;

    const int t = s[((b * 32 + x) * 32 + y) * 32 + z];
    const bool na = non_air(t);
    const int scount = __popcll(__ballot(na));   // non-air tokens in patch

    int c = 0, minj = 64;
    #pragma unroll 8
    for (int j = 0; j < 64; ++j) {
        const int tj = __shfl(t, j, 64);
        if (tj == t) { ++c; if (j < minj) minj = j; }
    }

    float e = 0.0f;
    if (na && minj == lane) {                    // first occurrence of this token
        const float p = (float)c / (float)(scount > 1 ? scount : 1);
        e = -p * logf(p + 1e-10f);
    }
    e = wave_reduce_f(e);
    if (lane == 0) atomicAdd(&acc[3], (double)e);
}

// --- smoothness: thread per float4 along Z; dy/dx neighbors via L2 ----------
__global__ void smooth_kernel(const float4* __restrict__ e4,
                              const float* __restrict__ e,
                              double* __restrict__ acc) {
    const int idx4 = blockIdx.x * blockDim.x + threadIdx.x;  // 16,777,216 float4s
    const int z4 = idx4 & 7;
    const int y  = (idx4 >> 3) & 31;
    const int x  = (idx4 >> 8) & 31;

    const float4 v = e4[idx4];

    float dz = fabsf(v.y - v.x) + fabsf(v.z - v.y) + fabsf(v.w - v.z);
    if (z4 < 7) dz += fabsf(e[idx4 * 4 + 4] - v.w);

    float dy = 0.0f;
    if (y < 31) {
        const float4 n = e4[idx4 + 8];
        dy = fabsf(n.x - v.x) + fabsf(n.y - v.y) + fabsf(n.z - v.z) + fabsf(n.w - v.w);
    }

    float dx = 0.0f;
    if (x < 31) {
        const float4 n = e4[idx4 + 256];
        dx = fabsf(n.x - v.x) + fabsf(n.y - v.y) + fabsf(n.z - v.z) + fabsf(n.w - v.w);
    }

    dx = wave_reduce_f(dx);
    dy = wave_reduce_f(dy);
    dz = wave_reduce_f(dz);

    __shared__ float smem[3][4];
    const int lane = threadIdx.x & 63, wid = threadIdx.x >> 6;
    if (lane == 0) { smem[0][wid] = dx; smem[1][wid] = dy; smem[2][wid] = dz; }
    __syncthreads();
    if (threadIdx.x == 0) {
        atomicAdd(&acc[4], (double)(smem[0][0] + smem[0][1] + smem[0][2] + smem[0][3]));
        atomicAdd(&acc[5], (double)(smem[1][0] + smem[1][1] + smem[1][2] + smem[1][3]));
        atomicAdd(&acc[6], (double)(smem[2][0] + smem[2][1] + smem[2][2] + smem[2][3]));
    }
}

// --- combine -----------------------------------------------------------------
__global__ void finalize_kernel(const double* __restrict__ acc, float* __restrict__ out) {
    const double na = acc[1];
    const double l_conn    = acc[0] / (na + 1e-6);
    const double l_support = acc[2] / (na + 1e-6);
    const double l_patch   = acc[3] / (32768.0 + 1e-6);
    const double nd = 65011712.0;  // 64*32*31*32*32 (same for dx, dy, dz)
    const double l_smooth  = (acc[4] / nd + acc[5] / nd + acc[6] / nd) / 3.0;
    const double total = 0.5 * l_conn + 0.3 * l_patch + 0.1 * l_smooth + 0.2 * l_support;
    out[0] = (float)total;
    out[1] = (float)l_conn;
    out[2] = (float)l_patch;
    out[3] = (float)l_smooth;
    out[4] = (float)l_support;
}

extern "C" void kernel_launch(void* const* d_in, const int* in_sizes, int n_in,
                              void* d_out, int out_size, void* d_ws, size_t ws_size,
                              hipStream_t stream) {
    const int*   s   = (const int*)d_in[0];
    const float* emb = (const float*)d_in[1];
    float* out  = (float*)d_out;
    double* acc = (double*)d_ws;

    hipMemsetAsync(acc, 0, 7 * sizeof(double), stream);

    // structure: 2,097,152 voxels
    struct_kernel<<<8192, 256, 0, stream>>>(s, acc);
    // patches: 32768 patches * 64 lanes = 2,097,152 threads
    patch_kernel<<<8192, 256, 0, stream>>>(s, acc);
    // embeddings: 16,777,216 float4s
    smooth_kernel<<<65536, 256, 0, stream>>>((const float4*)emb, emb, acc);

    finalize_kernel<<<1, 1, 0, stream>>>(acc, out);
}

// Round 2
// 514.472 us; speedup vs baseline: 6.1329x; 6.1329x over previous
//
#include <hip/hip_runtime.h>

// ---------------------------------------------------------------------------
// StructuralCoherenceLoss on MI355X
// Inputs:  d_in[0] structure        int32  [64,32,32,32]
//          d_in[1] block_embeddings f32    [64,32,32,32,32]  (B,C,X,Y,Z)
// Output:  d_out   f32 [5] = (total, l_conn, l_patch, l_smooth, l_support)
//
// No global atomics: each block writes deterministic partials into d_ws
// (doubles), finalize_kernel reduces them.
//
// Workspace layout (doubles):
//   [0,2048)      smooth dx partials      (SM_BLOCKS = 2048)
//   [2048,4096)   smooth dy partials
//   [4096,6144)   smooth dz partials
//   [6144,6400)   struct isolated partials (ST_BLOCKS = 256)
//   [6400,6656)   struct non-air partials
//   [6656,6912)   struct unsupported partials
//   [6912,7168)   patch entropy partials   (PA_BLOCKS = 256)
// Total: 7168 doubles = 56 KB.
// ---------------------------------------------------------------------------

#define SM_BLOCKS 2048
#define ST_BLOCKS 256
#define PA_BLOCKS 256
#define WS_DX 0
#define WS_DY (SM_BLOCKS)
#define WS_DZ (2 * SM_BLOCKS)
#define WS_ISO (3 * SM_BLOCKS)
#define WS_NA (WS_ISO + ST_BLOCKS)
#define WS_UNS (WS_NA + ST_BLOCKS)
#define WS_ENT (WS_UNS + ST_BLOCKS)

__device__ __forceinline__ bool non_air(int t) {
    return !(t == 102 || t == 576 || t == 3352);
}

__device__ __forceinline__ double wave_red_d(double v) {
    #pragma unroll
    for (int off = 32; off > 0; off >>= 1) v += __shfl_down(v, off, 64);
    return v;
}
__device__ __forceinline__ float wave_red_f(float v) {
    #pragma unroll
    for (int off = 32; off > 0; off >>= 1) v += __shfl_down(v, off, 64);
    return v;
}
__device__ __forceinline__ int wave_red_i(int v) {
    #pragma unroll
    for (int off = 32; off > 0; off >>= 1) v += __shfl_down(v, off, 64);
    return v;
}

// --- smoothness: grid-stride over 16,777,216 float4s ------------------------
__global__ __launch_bounds__(256) void smooth_kernel(const float4* __restrict__ e4,
                                                     double* __restrict__ part) {
    double adx = 0.0, ady = 0.0, adz = 0.0;
    const int stride = SM_BLOCKS * 256;
    for (int idx4 = blockIdx.x * 256 + threadIdx.x; idx4 < (1 << 24); idx4 += stride) {
        const int z4 = idx4 & 7;
        const int y = (idx4 >> 3) & 31;
        const int x = (idx4 >> 8) & 31;

        const float4 v = e4[idx4];

        // z-neighbor's first element lives in lane+1 (z4<7 implies lane&7 < 7)
        const float nxt = __shfl_down(v.x, 1, 64);
        float dz = fabsf(v.y - v.x) + fabsf(v.z - v.y) + fabsf(v.w - v.z);
        if (z4 < 7) dz += fabsf(nxt - v.w);

        float dy = 0.0f;
        if (y < 31) {
            const float4 n = e4[idx4 + 8];
            dy = fabsf(n.x - v.x) + fabsf(n.y - v.y) + fabsf(n.z - v.z) + fabsf(n.w - v.w);
        }
        float dx = 0.0f;
        if (x < 31) {
            const float4 n = e4[idx4 + 256];
            dx = fabsf(n.x - v.x) + fabsf(n.y - v.y) + fabsf(n.z - v.z) + fabsf(n.w - v.w);
        }
        adx += dx; ady += dy; adz += dz;
    }

    adx = wave_red_d(adx); ady = wave_red_d(ady); adz = wave_red_d(adz);
    __shared__ double sm[3][4];
    const int lane = threadIdx.x & 63, wid = threadIdx.x >> 6;
    if (lane == 0) { sm[0][wid] = adx; sm[1][wid] = ady; sm[2][wid] = adz; }
    __syncthreads();
    if (threadIdx.x == 0) {
        part[WS_DX + blockIdx.x] = sm[0][0] + sm[0][1] + sm[0][2] + sm[0][3];
        part[WS_DY + blockIdx.x] = sm[1][0] + sm[1][1] + sm[1][2] + sm[1][3];
        part[WS_DZ + blockIdx.x] = sm[2][0] + sm[2][1] + sm[2][2] + sm[2][3];
    }
}

// --- connectivity + support: grid-stride over 2,097,152 voxels --------------
__global__ __launch_bounds__(256) void struct_kernel(const int* __restrict__ s,
                                                     double* __restrict__ part) {
    int iso = 0, nai = 0, unsup = 0;
    const int stride = ST_BLOCKS * 256;
    for (int idx = blockIdx.x * 256 + threadIdx.x; idx < (1 << 21); idx += stride) {
        const int z = idx & 31;
        const int y = (idx >> 5) & 31;
        const int x = (idx >> 10) & 31;
        const int t = s[idx];
        if (non_air(t)) {
            ++nai;
            int ncnt = 0;
            bool below = false;
            if (x > 0)  ncnt += non_air(s[idx - 1024]);
            if (x < 31) ncnt += non_air(s[idx + 1024]);
            if (y > 0)  { below = non_air(s[idx - 32]); ncnt += below; }
            if (y < 31) ncnt += non_air(s[idx + 32]);
            if (z > 0)  ncnt += non_air(s[idx - 1]);
            if (z < 31) ncnt += non_air(s[idx + 1]);
            iso += (ncnt == 0);
            unsup += (y > 0 && !below);
        }
    }
    iso = wave_red_i(iso); nai = wave_red_i(nai); unsup = wave_red_i(unsup);
    __shared__ int sm[3][4];
    const int lane = threadIdx.x & 63, wid = threadIdx.x >> 6;
    if (lane == 0) { sm[0][wid] = iso; sm[1][wid] = nai; sm[2][wid] = unsup; }
    __syncthreads();
    if (threadIdx.x == 0) {
        part[WS_ISO + blockIdx.x] = (double)(sm[0][0] + sm[0][1] + sm[0][2] + sm[0][3]);
        part[WS_NA  + blockIdx.x] = (double)(sm[1][0] + sm[1][1] + sm[1][2] + sm[1][3]);
        part[WS_UNS + blockIdx.x] = (double)(sm[2][0] + sm[2][1] + sm[2][2] + sm[2][3]);
    }
}

// --- per-patch entropy: one wave per 4x4x4 patch, grid-stride over patches --
__global__ __launch_bounds__(256) void patch_kernel(const int* __restrict__ s,
                                                    double* __restrict__ part) {
    const int lane = threadIdx.x & 63, wid = threadIdx.x >> 6;
    const int gwave = blockIdx.x * 4 + wid;
    const int nwaves = PA_BLOCKS * 4;
    const int px = lane >> 4, py = (lane >> 2) & 3, pz = lane & 3;

    float esum = 0.0f;
    for (int pid = gwave; pid < 32768; pid += nwaves) {
        const int b = pid >> 9;
        const int rem = pid & 511;
        const int ix = rem >> 6, iy = (rem >> 3) & 7, iz = rem & 7;
        const int x = ix * 4 + px, y = iy * 4 + py, z = iz * 4 + pz;

        const int t = s[((b * 32 + x) * 32 + y) * 32 + z];
        const bool na = non_air(t);
        const int scount = __popcll(__ballot(na));

        int c = 0, minj = 64;
        #pragma unroll 8
        for (int j = 0; j < 64; ++j) {
            const int tj = __shfl(t, j, 64);
            if (tj == t) { ++c; if (j < minj) minj = j; }
        }
        if (na && minj == lane) {  // first occurrence of this token in the patch
            const float p = (float)c / (float)(scount > 1 ? scount : 1);
            esum += -p * logf(p + 1e-10f);
        }
    }
    const float w = wave_red_f(esum);
    __shared__ float sm[4];
    if (lane == 0) sm[wid] = w;
    __syncthreads();
    if (threadIdx.x == 0)
        part[WS_ENT + blockIdx.x] = (double)(sm[0] + sm[1] + sm[2] + sm[3]);
}

// --- combine -----------------------------------------------------------------
__global__ __launch_bounds__(256) void finalize_kernel(const double* __restrict__ part,
                                                       float* __restrict__ out) {
    __shared__ double sm[4];
    __shared__ double res[7];
    const int lane = threadIdx.x & 63, wid = threadIdx.x >> 6;
    const int base[7] = {WS_DX, WS_DY, WS_DZ, WS_ISO, WS_NA, WS_UNS, WS_ENT};
    const int len[7]  = {SM_BLOCKS, SM_BLOCKS, SM_BLOCKS, ST_BLOCKS, ST_BLOCKS, ST_BLOCKS, PA_BLOCKS};
    for (int k = 0; k < 7; ++k) {
        double a = 0.0;
        for (int i = threadIdx.x; i < len[k]; i += 256) a += part[base[k] + i];
        a = wave_red_d(a);
        if (lane == 0) sm[wid] = a;
        __syncthreads();
        if (threadIdx.x == 0) res[k] = sm[0] + sm[1] + sm[2] + sm[3];
        __syncthreads();
    }
    if (threadIdx.x == 0) {
        const double na = res[4];
        const double l_conn    = res[3] / (na + 1e-6);
        const double l_support = res[5] / (na + 1e-6);
        const double l_patch   = res[6] / (32768.0 + 1e-6);
        const double nd = 65011712.0;  // 64*32*31*32*32 (same for dx, dy, dz)
        const double l_smooth  = (res[0] / nd + res[1] / nd + res[2] / nd) / 3.0;
        const double total = 0.5 * l_conn + 0.3 * l_patch + 0.1 * l_smooth + 0.2 * l_support;
        out[0] = (float)total;
        out[1] = (float)l_conn;
        out[2] = (float)l_patch;
        out[3] = (float)l_smooth;
        out[4] = (float)l_support;
    }
}

extern "C" void kernel_launch(void* const* d_in, const int* in_sizes, int n_in,
                              void* d_out, int out_size, void* d_ws, size_t ws_size,
                              hipStream_t stream) {
    const int*   s   = (const int*)d_in[0];
    const float* emb = (const float*)d_in[1];
    float* out   = (float*)d_out;
    double* part = (double*)d_ws;

    struct_kernel<<<ST_BLOCKS, 256, 0, stream>>>(s, part);
    patch_kernel<<<PA_BLOCKS, 256, 0, stream>>>(s, part);
    smooth_kernel<<<SM_BLOCKS, 256, 0, stream>>>((const float4*)emb, part);
    finalize_kernel<<<1, 256, 0, stream>>>(part, out);
}

// Round 3
// 437.601 us; speedup vs baseline: 7.2103x; 1.1757x over previous
//
#include <hip/hip_runtime.h>

// ---------------------------------------------------------------------------
// StructuralCoherenceLoss on MI355X
// Inputs:  d_in[0] structure        int32  [64,32,32,32]
//          d_in[1] block_embeddings f32    [64,32,32,32,32]  (B,C,X,Y,Z)
// Output:  d_out   f32 [5] = (total, l_conn, l_patch, l_smooth, l_support)
//
// One fused main kernel (block-uniform branch on blockIdx range):
//   blocks [0, SM)            : smoothness (grid-stride over float4s)
//   blocks [SM, SM+ST)        : connectivity + support
//   blocks [SM+ST, SM+ST+PA)  : patch entropy (one wave per 4^3 patch)
// then a tiny finalize kernel. No global atomics; deterministic partials.
//
// Workspace (doubles):
//   [0,2048)      dx partials          (SM = 2048)
//   [2048,4096)   dy partials
//   [4096,6144)   dz partials
//   [6144,7168)   isolated partials    (ST = 1024)
//   [7168,8192)   non-air partials
//   [8192,9216)   unsupported partials
//   [9216,9728)   entropy partials     (PA = 512)
// ---------------------------------------------------------------------------

#define SM_BLOCKS 2048
#define ST_BLOCKS 1024
#define PA_BLOCKS 512
#define WS_DX  0
#define WS_DY  (SM_BLOCKS)
#define WS_DZ  (2 * SM_BLOCKS)
#define WS_ISO (3 * SM_BLOCKS)
#define WS_NA  (WS_ISO + ST_BLOCKS)
#define WS_UNS (WS_NA + ST_BLOCKS)
#define WS_ENT (WS_UNS + ST_BLOCKS)

__device__ __forceinline__ bool non_air(int t) {
    return !(t == 102 || t == 576 || t == 3352);
}

__device__ __forceinline__ double wave_red_d(double v) {
    #pragma unroll
    for (int off = 32; off > 0; off >>= 1) v += __shfl_down(v, off, 64);
    return v;
}
__device__ __forceinline__ float wave_red_f(float v) {
    #pragma unroll
    for (int off = 32; off > 0; off >>= 1) v += __shfl_down(v, off, 64);
    return v;
}
__device__ __forceinline__ int wave_red_i(int v) {
    #pragma unroll
    for (int off = 32; off > 0; off >>= 1) v += __shfl_down(v, off, 64);
    return v;
}

// --- smoothness body: grid-stride over 16,777,216 float4s -------------------
__device__ void smooth_body(const float4* __restrict__ e4,
                            double* __restrict__ part, int bid) {
    double adx = 0.0, ady = 0.0, adz = 0.0;
    const int stride = SM_BLOCKS * 256;
    for (int idx4 = bid * 256 + (int)threadIdx.x; idx4 < (1 << 24); idx4 += stride) {
        const int z4 = idx4 & 7;
        const int y = (idx4 >> 3) & 31;
        const int x = (idx4 >> 8) & 31;

        const float4 v = e4[idx4];

        // z-neighbor's first element lives in lane+1 (z4<7 implies lane&7 < 7)
        const float nxt = __shfl_down(v.x, 1, 64);
        float dz = fabsf(v.y - v.x) + fabsf(v.z - v.y) + fabsf(v.w - v.z);
        if (z4 < 7) dz += fabsf(nxt - v.w);

        float dy = 0.0f;
        if (y < 31) {
            const float4 n = e4[idx4 + 8];
            dy = fabsf(n.x - v.x) + fabsf(n.y - v.y) + fabsf(n.z - v.z) + fabsf(n.w - v.w);
        }
        float dx = 0.0f;
        if (x < 31) {
            const float4 n = e4[idx4 + 256];
            dx = fabsf(n.x - v.x) + fabsf(n.y - v.y) + fabsf(n.z - v.z) + fabsf(n.w - v.w);
        }
        adx += dx; ady += dy; adz += dz;
    }

    adx = wave_red_d(adx); ady = wave_red_d(ady); adz = wave_red_d(adz);
    __shared__ double sm[3][4];
    const int lane = threadIdx.x & 63, wid = threadIdx.x >> 6;
    if (lane == 0) { sm[0][wid] = adx; sm[1][wid] = ady; sm[2][wid] = adz; }
    __syncthreads();
    if (threadIdx.x == 0) {
        part[WS_DX + bid] = sm[0][0] + sm[0][1] + sm[0][2] + sm[0][3];
        part[WS_DY + bid] = sm[1][0] + sm[1][1] + sm[1][2] + sm[1][3];
        part[WS_DZ + bid] = sm[2][0] + sm[2][1] + sm[2][2] + sm[2][3];
    }
}

// --- connectivity + support body: grid-stride over 2,097,152 voxels ---------
__device__ void struct_body(const int* __restrict__ s,
                            double* __restrict__ part, int bid) {
    int iso = 0, nai = 0, unsup = 0;
    const int stride = ST_BLOCKS * 256;
    for (int idx = bid * 256 + (int)threadIdx.x; idx < (1 << 21); idx += stride) {
        const int z = idx & 31;
        const int y = (idx >> 5) & 31;
        const int x = (idx >> 10) & 31;
        const int t = s[idx];
        if (non_air(t)) {
            ++nai;
            int ncnt = 0;
            bool below = false;
            if (x > 0)  ncnt += non_air(s[idx - 1024]);
            if (x < 31) ncnt += non_air(s[idx + 1024]);
            if (y > 0)  { below = non_air(s[idx - 32]); ncnt += below; }
            if (y < 31) ncnt += non_air(s[idx + 32]);
            if (z > 0)  ncnt += non_air(s[idx - 1]);
            if (z < 31) ncnt += non_air(s[idx + 1]);
            iso += (ncnt == 0);
            unsup += (y > 0 && !below);
        }
    }
    iso = wave_red_i(iso); nai = wave_red_i(nai); unsup = wave_red_i(unsup);
    __shared__ int sm[3][4];
    const int lane = threadIdx.x & 63, wid = threadIdx.x >> 6;
    if (lane == 0) { sm[0][wid] = iso; sm[1][wid] = nai; sm[2][wid] = unsup; }
    __syncthreads();
    if (threadIdx.x == 0) {
        part[WS_ISO + bid] = (double)(sm[0][0] + sm[0][1] + sm[0][2] + sm[0][3]);
        part[WS_NA  + bid] = (double)(sm[1][0] + sm[1][1] + sm[1][2] + sm[1][3]);
        part[WS_UNS + bid] = (double)(sm[2][0] + sm[2][1] + sm[2][2] + sm[2][3]);
    }
}

// --- patch entropy body: one wave per 4x4x4 patch, grid-stride over patches -
__device__ void patch_body(const int* __restrict__ s,
                           double* __restrict__ part, int bid) {
    const int lane = threadIdx.x & 63, wid = threadIdx.x >> 6;
    const int gwave = bid * 4 + wid;
    const int nwaves = PA_BLOCKS * 4;
    const int px = lane >> 4, py = (lane >> 2) & 3, pz = lane & 3;

    float esum = 0.0f;
    for (int pid = gwave; pid < 32768; pid += nwaves) {   // uniform trip count per wave
        const int b = pid >> 9;
        const int rem = pid & 511;
        const int ix = rem >> 6, iy = (rem >> 3) & 7, iz = rem & 7;
        const int x = ix * 4 + px, y = iy * 4 + py, z = iz * 4 + pz;

        const int t = s[((b * 32 + x) * 32 + y) * 32 + z];
        const bool na = non_air(t);
        const int scount = __popcll(__ballot(na));

        int c = 0, minj = 64;
        #pragma unroll 8
        for (int j = 0; j < 64; ++j) {
            const int tj = __shfl(t, j, 64);
            if (tj == t) { ++c; if (j < minj) minj = j; }
        }
        if (na && minj == lane) {  // first occurrence of this token in the patch
            const float p = (float)c / (float)(scount > 1 ? scount : 1);
            esum += -p * logf(p + 1e-10f);
        }
    }
    const float w = wave_red_f(esum);
    __shared__ float smp[4];
    if (lane == 0) smp[wid] = w;
    __syncthreads();
    if (threadIdx.x == 0)
        part[WS_ENT + bid] = (double)(smp[0] + smp[1] + smp[2] + smp[3]);
}

// --- fused main kernel -------------------------------------------------------
__global__ __launch_bounds__(256) void fused_kernel(const int* __restrict__ s,
                                                    const float4* __restrict__ e4,
                                                    double* __restrict__ part) {
    const int bid = blockIdx.x;
    if (bid < SM_BLOCKS) {
        smooth_body(e4, part, bid);
    } else if (bid < SM_BLOCKS + ST_BLOCKS) {
        struct_body(s, part, bid - SM_BLOCKS);
    } else {
        patch_body(s, part, bid - SM_BLOCKS - ST_BLOCKS);
    }
}

// --- combine -----------------------------------------------------------------
__global__ __launch_bounds__(256) void finalize_kernel(const double* __restrict__ part,
                                                       float* __restrict__ out) {
    __shared__ double sm[4];
    __shared__ double res[7];
    const int lane = threadIdx.x & 63, wid = threadIdx.x >> 6;
    const int base[7] = {WS_DX, WS_DY, WS_DZ, WS_ISO, WS_NA, WS_UNS, WS_ENT};
    const int len[7]  = {SM_BLOCKS, SM_BLOCKS, SM_BLOCKS, ST_BLOCKS, ST_BLOCKS, ST_BLOCKS, PA_BLOCKS};
    for (int k = 0; k < 7; ++k) {
        double a = 0.0;
        for (int i = threadIdx.x; i < len[k]; i += 256) a += part[base[k] + i];
        a = wave_red_d(a);
        if (lane == 0) sm[wid] = a;
        __syncthreads();
        if (threadIdx.x == 0) res[k] = sm[0] + sm[1] + sm[2] + sm[3];
        __syncthreads();
    }
    if (threadIdx.x == 0) {
        const double na = res[4];
        const double l_conn    = res[3] / (na + 1e-6);
        const double l_support = res[5] / (na + 1e-6);
        const double l_patch   = res[6] / (32768.0 + 1e-6);
        const double nd = 65011712.0;  // 64*32*31*32*32 (same for dx, dy, dz)
        const double l_smooth  = (res[0] / nd + res[1] / nd + res[2] / nd) / 3.0;
        const double total = 0.5 * l_conn + 0.3 * l_patch + 0.1 * l_smooth + 0.2 * l_support;
        out[0] = (float)total;
        out[1] = (float)l_conn;
        out[2] = (float)l_patch;
        out[3] = (float)l_smooth;
        out[4] = (float)l_support;
    }
}

extern "C" void kernel_launch(void* const* d_in, const int* in_sizes, int n_in,
                              void* d_out, int out_size, void* d_ws, size_t ws_size,
                              hipStream_t stream) {
    const int*   s   = (const int*)d_in[0];
    const float* emb = (const float*)d_in[1];
    float* out   = (float*)d_out;
    double* part = (double*)d_ws;

    fused_kernel<<<SM_BLOCKS + ST_BLOCKS + PA_BLOCKS, 256, 0, stream>>>(
        s, (const float4*)emb, part);
    finalize_kernel<<<1, 256, 0, stream>>>(part, out);
}

// Round 4
// 389.181 us; speedup vs baseline: 8.1074x; 1.1244x over previous
//
#include <hip/hip_runtime.h>

// ---------------------------------------------------------------------------
// StructuralCoherenceLoss on MI355X
// Inputs:  d_in[0] structure        int32  [64,32,32,32]
//          d_in[1] block_embeddings f32    [64,32,32,32,32]  (B,C,X,Y,Z)
// Output:  d_out   f32 [5] = (total, l_conn, l_patch, l_smooth, l_support)
//
// One fused main kernel, block ranges (patch/struct FIRST so they hide under
// the smooth stream instead of forming a tail):
//   blocks [0, PA)                 : patch entropy (one wave per 4^3 patch)
//   blocks [PA, PA+ST)             : connectivity + support
//   blocks [PA+ST, PA+ST+SM)       : smoothness
// then a tiny finalize kernel. No global atomics; deterministic partials.
//
// Smooth key facts: thread-id space = 2^19 = grid stride, so z4/y/x
// (bits 0..12 of idx4) are LOOP-INVARIANT per thread -> masks/offsets hoisted,
// branch-free inner loop (clamped neighbor offset => self-diff = 0), float
// accumulation, manual x2 unroll for load batching.
//
// Workspace (doubles):
//   [0,2048)      dx partials          (SM = 2048)
//   [2048,4096)   dy partials
//   [4096,6144)   dz partials
//   [6144,6656)   isolated partials    (ST = 512)
//   [6656,7168)   non-air partials
//   [7168,7680)   unsupported partials
//   [7680,7936)   entropy partials     (PA = 256)
// ---------------------------------------------------------------------------

#define SM_BLOCKS 2048
#define ST_BLOCKS 512
#define PA_BLOCKS 256
#define WS_DX  0
#define WS_DY  (SM_BLOCKS)
#define WS_DZ  (2 * SM_BLOCKS)
#define WS_ISO (3 * SM_BLOCKS)
#define WS_NA  (WS_ISO + ST_BLOCKS)
#define WS_UNS (WS_NA + ST_BLOCKS)
#define WS_ENT (WS_UNS + ST_BLOCKS)

__device__ __forceinline__ bool non_air(int t) {
    return !(t == 102 || t == 576 || t == 3352);
}

__device__ __forceinline__ double wave_red_d(double v) {
    #pragma unroll
    for (int off = 32; off > 0; off >>= 1) v += __shfl_down(v, off, 64);
    return v;
}
__device__ __forceinline__ float wave_red_f(float v) {
    #pragma unroll
    for (int off = 32; off > 0; off >>= 1) v += __shfl_down(v, off, 64);
    return v;
}
__device__ __forceinline__ int wave_red_i(int v) {
    #pragma unroll
    for (int off = 32; off > 0; off >>= 1) v += __shfl_down(v, off, 64);
    return v;
}

__device__ __forceinline__ float sad4(float4 a, float4 b) {
    return fabsf(a.x - b.x) + fabsf(a.y - b.y) + fabsf(a.z - b.z) + fabsf(a.w - b.w);
}

// --- smoothness body: 2048 blocks, 32 iterations/thread, branch-free --------
__device__ void smooth_body(const float* __restrict__ e,
                            const float4* __restrict__ e4,
                            double* __restrict__ part, int bid) {
    const int t0 = bid * 256 + (int)threadIdx.x;       // < 2^19; bits 0..18 fixed
    const int z4 = t0 & 7;
    const int y  = (t0 >> 3) & 31;
    const int x  = (t0 >> 8) & 31;
    // loop-invariant neighbor offsets; 0 => neighbor==self => diff contributes 0
    const int   oy  = (y < 31) ? 8 : 0;
    const int   ox  = (x < 31) ? 256 : 0;
    const int   oz  = (z4 < 7) ? 4 : 0;
    const float mzf = (z4 < 7) ? 1.0f : 0.0f;

    float ax = 0.0f, ay = 0.0f, az = 0.0f;
    const int S = 1 << 19;

    #pragma unroll 1
    for (int k = 0; k < 32; k += 2) {
        const int i0 = t0 + k * S;
        const int i1 = i0 + S;
        // issue all 8 loads up front (independent)
        const float4 v0 = e4[i0];
        const float4 v1 = e4[i1];
        const float4 py0 = e4[i0 + oy];
        const float4 py1 = e4[i1 + oy];
        const float4 px0 = e4[i0 + ox];
        const float4 px1 = e4[i1 + ox];
        const float  f0 = e[(i0 << 2) + oz];   // z-forward peek (L1 hit)
        const float  f1 = e[(i1 << 2) + oz];

        az += fabsf(v0.y - v0.x) + fabsf(v0.z - v0.y) + fabsf(v0.w - v0.z)
            + mzf * fabsf(f0 - v0.w);
        az += fabsf(v1.y - v1.x) + fabsf(v1.z - v1.y) + fabsf(v1.w - v1.z)
            + mzf * fabsf(f1 - v1.w);
        ay += sad4(py0, v0) + sad4(py1, v1);
        ax += sad4(px0, v0) + sad4(px1, v1);
    }

    double dxd = wave_red_d((double)ax);
    double dyd = wave_red_d((double)ay);
    double dzd = wave_red_d((double)az);
    __shared__ double sm[3][4];
    const int lane = threadIdx.x & 63, wid = threadIdx.x >> 6;
    if (lane == 0) { sm[0][wid] = dxd; sm[1][wid] = dyd; sm[2][wid] = dzd; }
    __syncthreads();
    if (threadIdx.x == 0) {
        part[WS_DX + bid] = sm[0][0] + sm[0][1] + sm[0][2] + sm[0][3];
        part[WS_DY + bid] = sm[1][0] + sm[1][1] + sm[1][2] + sm[1][3];
        part[WS_DZ + bid] = sm[2][0] + sm[2][1] + sm[2][2] + sm[2][3];
    }
}

// --- connectivity + support: 512 blocks, 16 iterations/thread ---------------
__device__ void struct_body(const int* __restrict__ s,
                            double* __restrict__ part, int bid) {
    const int t0 = bid * 256 + (int)threadIdx.x;   // < 2^17; bits 0..16 fixed
    const int z = t0 & 31, y = (t0 >> 5) & 31, x = (t0 >> 10) & 31;
    int iso = 0, nai = 0, unsup = 0;
    #pragma unroll 2
    for (int k = 0; k < 16; ++k) {
        const int idx = t0 + (k << 17);
        const int t = s[idx];
        if (non_air(t)) {
            ++nai;
            int ncnt = 0;
            bool below = false;
            if (x > 0)  ncnt += non_air(s[idx - 1024]);
            if (x < 31) ncnt += non_air(s[idx + 1024]);
            if (y > 0)  { below = non_air(s[idx - 32]); ncnt += below; }
            if (y < 31) ncnt += non_air(s[idx + 32]);
            if (z > 0)  ncnt += non_air(s[idx - 1]);
            if (z < 31) ncnt += non_air(s[idx + 1]);
            iso += (ncnt == 0);
            unsup += (y > 0 && !below);
        }
    }
    iso = wave_red_i(iso); nai = wave_red_i(nai); unsup = wave_red_i(unsup);
    __shared__ int sm[3][4];
    const int lane = threadIdx.x & 63, wid = threadIdx.x >> 6;
    if (lane == 0) { sm[0][wid] = iso; sm[1][wid] = nai; sm[2][wid] = unsup; }
    __syncthreads();
    if (threadIdx.x == 0) {
        part[WS_ISO + bid] = (double)(sm[0][0] + sm[0][1] + sm[0][2] + sm[0][3]);
        part[WS_NA  + bid] = (double)(sm[1][0] + sm[1][1] + sm[1][2] + sm[1][3]);
        part[WS_UNS + bid] = (double)(sm[2][0] + sm[2][1] + sm[2][2] + sm[2][3]);
    }
}

// --- patch entropy: one wave per 4x4x4 patch, 32 patches/wave ---------------
__device__ void patch_body(const int* __restrict__ s,
                           double* __restrict__ part, int bid) {
    const int lane = threadIdx.x & 63, wid = threadIdx.x >> 6;
    const int gwave = bid * 4 + wid;
    const int nwaves = PA_BLOCKS * 4;
    const int px = lane >> 4, py = (lane >> 2) & 3, pz = lane & 3;

    float esum = 0.0f;
    for (int pid = gwave; pid < 32768; pid += nwaves) {
        const int b = pid >> 9;
        const int rem = pid & 511;
        const int ix = rem >> 6, iy = (rem >> 3) & 7, iz = rem & 7;
        const int x = ix * 4 + px, y = iy * 4 + py, z = iz * 4 + pz;

        const int t = s[((b * 32 + x) * 32 + y) * 32 + z];
        const bool na = non_air(t);
        const int scount = __popcll(__ballot(na));

        int c = 0, minj = 64;
        #pragma unroll 8
        for (int j = 0; j < 64; ++j) {
            const int tj = __shfl(t, j, 64);
            if (tj == t) { ++c; if (j < minj) minj = j; }
        }
        if (na && minj == lane) {  // first occurrence of this token in the patch
            const float p = (float)c / (float)(scount > 1 ? scount : 1);
            esum += -p * logf(p + 1e-10f);
        }
    }
    const float w = wave_red_f(esum);
    __shared__ float smp[4];
    if (lane == 0) smp[wid] = w;
    __syncthreads();
    if (threadIdx.x == 0)
        part[WS_ENT + bid] = (double)(smp[0] + smp[1] + smp[2] + smp[3]);
}

// --- fused main kernel (patch/struct first => no tail) ----------------------
__global__ __launch_bounds__(256) void fused_kernel(const int* __restrict__ s,
                                                    const float* __restrict__ e,
                                                    const float4* __restrict__ e4,
                                                    double* __restrict__ part) {
    const int bid = blockIdx.x;
    if (bid < PA_BLOCKS) {
        patch_body(s, part, bid);
    } else if (bid < PA_BLOCKS + ST_BLOCKS) {
        struct_body(s, part, bid - PA_BLOCKS);
    } else {
        smooth_body(e, e4, part, bid - PA_BLOCKS - ST_BLOCKS);
    }
}

// --- combine -----------------------------------------------------------------
__global__ __launch_bounds__(256) void finalize_kernel(const double* __restrict__ part,
                                                       float* __restrict__ out) {
    __shared__ double sm[4];
    __shared__ double res[7];
    const int lane = threadIdx.x & 63, wid = threadIdx.x >> 6;
    const int base[7] = {WS_DX, WS_DY, WS_DZ, WS_ISO, WS_NA, WS_UNS, WS_ENT};
    const int len[7]  = {SM_BLOCKS, SM_BLOCKS, SM_BLOCKS, ST_BLOCKS, ST_BLOCKS, ST_BLOCKS, PA_BLOCKS};
    for (int k = 0; k < 7; ++k) {
        double a = 0.0;
        for (int i = threadIdx.x; i < len[k]; i += 256) a += part[base[k] + i];
        a = wave_red_d(a);
        if (lane == 0) sm[wid] = a;
        __syncthreads();
        if (threadIdx.x == 0) res[k] = sm[0] + sm[1] + sm[2] + sm[3];
        __syncthreads();
    }
    if (threadIdx.x == 0) {
        const double na = res[4];
        const double l_conn    = res[3] / (na + 1e-6);
        const double l_support = res[5] / (na + 1e-6);
        const double l_patch   = res[6] / (32768.0 + 1e-6);
        const double nd = 65011712.0;  // 64*32*31*32*32 (same for dx, dy, dz)
        const double l_smooth  = (res[0] / nd + res[1] / nd + res[2] / nd) / 3.0;
        const double total = 0.5 * l_conn + 0.3 * l_patch + 0.1 * l_smooth + 0.2 * l_support;
        out[0] = (float)total;
        out[1] = (float)l_conn;
        out[2] = (float)l_patch;
        out[3] = (float)l_smooth;
        out[4] = (float)l_support;
    }
}

extern "C" void kernel_launch(void* const* d_in, const int* in_sizes, int n_in,
                              void* d_out, int out_size, void* d_ws, size_t ws_size,
                              hipStream_t stream) {
    const int*   s   = (const int*)d_in[0];
    const float* emb = (const float*)d_in[1];
    float* out   = (float*)d_out;
    double* part = (double*)d_ws;

    fused_kernel<<<PA_BLOCKS + ST_BLOCKS + SM_BLOCKS, 256, 0, stream>>>(
        s, emb, (const float4*)emb, part);
    finalize_kernel<<<1, 256, 0, stream>>>(part, out);
}